// Round 10
// baseline (372.438 us; speedup 1.0000x reference)
//
#include <hip/hip_runtime.h>
#include <math.h>

constexpr int NB = 8;
constexpr int NC = 256;
constexpr int NCR = 64;
constexpr int NH = 160;
constexpr int NW = 160;
constexpr int NHW = NH * NW;           // 25600
constexpr float KEPS = 1e-4f;

constexpr int TW = 32;                 // tile width (k_logits)
constexpr int TH = 8;                  // tile height (k_logits)

// K0: transpose rw[d][c] -> rwT[c][d]; block 0 also zeroes pooledsum
__global__ __launch_bounds__(256) void k_tr(const float* __restrict__ rw,
                                            float* __restrict__ rwT,
                                            float* __restrict__ pooledsum) {
    const int i = blockIdx.x * 256 + threadIdx.x;    // over 16384
    const int d = i >> 8, c = i & 255;
    rwT[c * NCR + d] = rw[i];
    if (blockIdx.x == 0) {
        pooledsum[threadIdx.x] = 0.f;
        pooledsum[256 + threadIdx.x] = 0.f;
    }
}

#define FMA4(A, X, W) \
    A.x = fmaf((X).x, (W), A.x); A.y = fmaf((X).y, (W), A.y); \
    A.z = fmaf((X).z, (W), A.z); A.w = fmaf((X).w, (W), A.w)

// R6 structure (8px x 16d per thread, all weights in 64KB LDS, 400 blocks)
// + depth-4 rotating x-prefetch: in-flight lookahead = ~4 channels x 256cy FMA
// = ~1024 cy >= L3/HBM latency (~900-1000cy). R6's depth-1 exposed ~1000cy
// per channel-iteration (measured: 230k of 360k cyc were stalls).
__global__ __launch_bounds__(256, 1) void k_reduce(const float* __restrict__ x,
                                                   const float* __restrict__ rwT,
                                                   float* __restrict__ y,
                                                   float* __restrict__ pooledsum) {
    __shared__ float wlds[NC * NCR];                 // 65536 B
    const int t = threadIdx.x;
    const int lane = t & 63;
    const int dg = t >> 6;                           // wave id = d-group 0..3
    const int b = blockIdx.y;
    const int p0 = blockIdx.x * 512 + lane * 4;      // px group0; group1 = +256

    {   // stage all 16384 weights: 4096 float4, 16 per thread
        const float4* src = reinterpret_cast<const float4*>(rwT);
        float4* dst = reinterpret_cast<float4*>(wlds);
#pragma unroll
        for (int i = 0; i < 16; ++i) dst[i * 256 + t] = src[i * 256 + t];
    }
    __syncthreads();

    const float* xb = x + (size_t)b * NC * NHW + p0;

    float4 Aa[16], Ab[16];
#pragma unroll
    for (int d = 0; d < 16; ++d) { Aa[d] = float4{0,0,0,0}; Ab[d] = float4{0,0,0,0}; }

    float4 xc[4][2];                                 // 4-channel-deep pipeline
#pragma unroll
    for (int j = 0; j < 4; ++j) {
        xc[j][0] = *reinterpret_cast<const float4*>(xb + (size_t)j * NHW);
        xc[j][1] = *reinterpret_cast<const float4*>(xb + (size_t)j * NHW + 256);
    }

    for (int cs = 0; cs < NC; cs += 4) {
#pragma unroll
        for (int j = 0; j < 4; ++j) {
            const int c = cs + j;
            const float4 u = xc[j][0], v = xc[j][1];
            // refill slot j with channel c+4 (clamped; tail loads are benign)
            const int cn = (c + 4 < NC) ? (c + 4) : (NC - 1);
            xc[j][0] = *reinterpret_cast<const float4*>(xb + (size_t)cn * NHW);
            xc[j][1] = *reinterpret_cast<const float4*>(xb + (size_t)cn * NHW + 256);

            const float4* wr = reinterpret_cast<const float4*>(wlds + c * NCR + dg * 16);
            const float4 w0 = wr[0], w1 = wr[1], w2 = wr[2], w3 = wr[3];
            FMA4(Aa[0],  u, w0.x); FMA4(Ab[0],  v, w0.x);
            FMA4(Aa[1],  u, w0.y); FMA4(Ab[1],  v, w0.y);
            FMA4(Aa[2],  u, w0.z); FMA4(Ab[2],  v, w0.z);
            FMA4(Aa[3],  u, w0.w); FMA4(Ab[3],  v, w0.w);
            FMA4(Aa[4],  u, w1.x); FMA4(Ab[4],  v, w1.x);
            FMA4(Aa[5],  u, w1.y); FMA4(Ab[5],  v, w1.y);
            FMA4(Aa[6],  u, w1.z); FMA4(Ab[6],  v, w1.z);
            FMA4(Aa[7],  u, w1.w); FMA4(Ab[7],  v, w1.w);
            FMA4(Aa[8],  u, w2.x); FMA4(Ab[8],  v, w2.x);
            FMA4(Aa[9],  u, w2.y); FMA4(Ab[9],  v, w2.y);
            FMA4(Aa[10], u, w2.z); FMA4(Ab[10], v, w2.z);
            FMA4(Aa[11], u, w2.w); FMA4(Ab[11], v, w2.w);
            FMA4(Aa[12], u, w3.x); FMA4(Ab[12], v, w3.x);
            FMA4(Aa[13], u, w3.y); FMA4(Ab[13], v, w3.y);
            FMA4(Aa[14], u, w3.z); FMA4(Ab[14], v, w3.z);
            FMA4(Aa[15], u, w3.w); FMA4(Ab[15], v, w3.w);
        }
    }

    float* yb = y + (size_t)b * NCR * NHW + (size_t)(dg * 16) * NHW + p0;
#pragma unroll
    for (int d = 0; d < 16; ++d) {
        *reinterpret_cast<float4*>(yb + (size_t)d * NHW) = Aa[d];
        *reinterpret_cast<float4*>(yb + (size_t)d * NHW + 256) = Ab[d];
    }

    float* ps = pooledsum + b * NCR + dg * 16;
#pragma unroll
    for (int d = 0; d < 16; ++d) {
        float s = Aa[d].x + Aa[d].y + Aa[d].z + Aa[d].w
                + Ab[d].x + Ab[d].y + Ab[d].z + Ab[d].w;
#pragma unroll
        for (int o = 32; o > 0; o >>= 1) s += __shfl_down(s, o, 64);
        if (lane == 0) atomicAdd(&ps[d], s);
    }
}

// K2: gamma[b,d] = sigmoid(relu(mean@w1^T+b1)@w2^T+b2); pooledsum -> mean
__global__ __launch_bounds__(512) void k_gate(const float* __restrict__ pooledsum,
                                              const float* __restrict__ w1,
                                              const float* __restrict__ b1,
                                              const float* __restrict__ w2,
                                              const float* __restrict__ b2,
                                              float* __restrict__ gamma) {
    __shared__ float hsh[NB][16];
    const int t = threadIdx.x;
    constexpr float inv = 1.f / (float)NHW;
    if (t < NB * 16) {
        const int b = t / 16, j = t % 16;
        float s = b1[j];
        for (int d = 0; d < NCR; ++d)
            s = fmaf(pooledsum[b * NCR + d] * inv, w1[j * NCR + d], s);
        hsh[b][j] = fmaxf(s, 0.f);
    }
    __syncthreads();
    const int b = t / NCR, d = t % NCR;
    float s = b2[d];
#pragma unroll
    for (int j = 0; j < 16; ++j) s = fmaf(hsh[b][j], w2[d * 16 + j], s);
    gamma[t] = 1.f / (1.f + expf(-s));
}

// K3a: per (b, 32x8 tile): stencil on y -> kappa -> logits -> m = 1+sigmoid
__global__ __launch_bounds__(256) void k_logits(const float* __restrict__ y,
                                                const float* __restrict__ gamma,
                                                const float* __restrict__ fw,
                                                float* __restrict__ m) {
    __shared__ float tile[TH + 2][TW + 2];           // 10 x 34
    __shared__ float coef[NCR];

    const int b = blockIdx.z;
    const int w0 = blockIdx.x * TW, h0 = blockIdx.y * TH;
    const int t = threadIdx.x;
    const int tx = t % TW, ty = t / TW;

    if (t < NCR) coef[t] = fw[t] + gamma[b * NCR + t] * fw[NCR + t];
    __syncthreads();

    const float* yb = y + (size_t)b * NCR * NHW;
    float logit = 0.f;

    for (int c = 0; c < NCR; ++c) {
        const float* yc = yb + (size_t)c * NHW;
        for (int i = t; i < (TH + 2) * (TW + 2); i += 256) {
            const int iy = i / (TW + 2), ix = i % (TW + 2);
            const int gh = h0 + iy - 1, gw = w0 + ix - 1;
            float v = 0.f;
            if (gh >= 0 && gh < NH && gw >= 0 && gw < NW) v = yc[gh * NW + gw];
            tile[iy][ix] = v;
        }
        __syncthreads();

        const float a00 = tile[ty][tx],     a01 = tile[ty][tx + 1],     a02 = tile[ty][tx + 2];
        const float a10 = tile[ty + 1][tx], a11 = tile[ty + 1][tx + 1], a12 = tile[ty + 1][tx + 2];
        const float a20 = tile[ty + 2][tx], a21 = tile[ty + 2][tx + 1], a22 = tile[ty + 2][tx + 2];

        const float mu = (a00 + a01 + a02 + a10 + a11 + a12 + a20 + a21 + a22) * (1.f / 9.f);
        const float gx = (a00 - a02 + 2.f * (a10 - a12) + a20 - a22) * 0.125f;
        const float gy = (a00 + 2.f * a01 + a02 - a20 - 2.f * a21 - a22) * 0.125f;
        const float kappa = 1.f - fabsf(a11 - mu) / (fabsf(gx) + fabsf(gy) + KEPS);
        logit = fmaf(kappa, coef[c], logit);
        __syncthreads();
    }

    const float a = 1.f / (1.f + expf(-logit));
    m[(size_t)b * NHW + (h0 + ty) * NW + (w0 + tx)] = 1.f + a;
}

// K3b: pure stream out = x * m. Block: 256 thr over 1024 px; 4 channels each.
__global__ __launch_bounds__(256) void k_mul(const float* __restrict__ x,
                                             const float* __restrict__ m,
                                             float* __restrict__ out) {
    const int b = blockIdx.z;
    const int c0 = blockIdx.y * 4;
    const int p = blockIdx.x * 1024 + threadIdx.x * 4;

    const float4 mv = *reinterpret_cast<const float4*>(m + (size_t)b * NHW + p);
    const size_t base = (size_t)b * NC * NHW + (size_t)c0 * NHW + p;
    const float* xp = x + base;
    float* op = out + base;

#pragma unroll
    for (int cc = 0; cc < 4; ++cc) {
        const float4 v = *reinterpret_cast<const float4*>(xp + (size_t)cc * NHW);
        float4 r;
        r.x = v.x * mv.x; r.y = v.y * mv.y; r.z = v.z * mv.z; r.w = v.w * mv.w;
        *reinterpret_cast<float4*>(op + (size_t)cc * NHW) = r;
    }
}

extern "C" void kernel_launch(void* const* d_in, const int* in_sizes, int n_in,
                              void* d_out, int out_size, void* d_ws, size_t ws_size,
                              hipStream_t stream) {
    const float* x  = (const float*)d_in[0];
    const float* rw = (const float*)d_in[1];
    const float* w1 = (const float*)d_in[2];
    const float* b1 = (const float*)d_in[3];
    const float* w2 = (const float*)d_in[4];
    const float* b2 = (const float*)d_in[5];
    const float* fw = (const float*)d_in[6];
    float* out = (float*)d_out;

    float* y      = (float*)d_ws;                       // 13,107,200 floats
    float* pooled = y + (size_t)NB * NCR * NHW;         // 512 floats (sums)
    float* gamma  = pooled + NB * NCR;                  // 512 floats
    float* rwT    = gamma + NB * NCR;                   // 16384 floats
    float* m      = rwT + NC * NCR;                     // 204800 floats

    k_tr<<<dim3(64), 256, 0, stream>>>(rw, rwT, pooled);
    k_reduce<<<dim3(NHW / 512, NB), 256, 0, stream>>>(x, rwT, y, pooled);
    k_gate<<<dim3(1), 512, 0, stream>>>(pooled, w1, b1, w2, b2, gamma);
    k_logits<<<dim3(NW / TW, NH / TH, NB), 256, 0, stream>>>(y, gamma, fw, m);
    k_mul<<<dim3(NHW / 1024, NC / 4, NB), 256, 0, stream>>>(x, m, out);
}

// Round 11
// 260.867 us; speedup vs baseline: 1.4277x; 1.4277x over previous
//
#include <hip/hip_runtime.h>
#include <math.h>

constexpr int NB = 8;
constexpr int NC = 256;
constexpr int NCR = 64;
constexpr int NH = 160;
constexpr int NW = 160;
constexpr int NHW = NH * NW;           // 25600
constexpr float KEPS = 1e-4f;

constexpr int TW = 32;                 // tile width (k_logits)
constexpr int TH = 8;                  // tile height (k_logits)

// K0: transpose rw[d][c] -> rwT[c][d]; block 0 also zeroes pooledsum
__global__ __launch_bounds__(256) void k_tr(const float* __restrict__ rw,
                                            float* __restrict__ rwT,
                                            float* __restrict__ pooledsum) {
    const int i = blockIdx.x * 256 + threadIdx.x;    // over 16384
    const int d = i >> 8, c = i & 255;
    rwT[c * NCR + d] = rw[i];
    if (blockIdx.x == 0) {
        pooledsum[threadIdx.x] = 0.f;
        pooledsum[256 + threadIdx.x] = 0.f;
    }
}

#define FMA4(A, X, W) \
    A.x = fmaf((X).x, (W), A.x); A.y = fmaf((X).y, (W), A.y); \
    A.z = fmaf((X).z, (W), A.z); A.w = fmaf((X).w, (W), A.w)

// one channel: 8 px (u,v) x 8 d (w0,w1) = 64 fmaf
#define KBODY8(U, V, W0, W1) \
    FMA4(A0, U, (W0).x); FMA4(A1, U, (W0).y); FMA4(A2, U, (W0).z); FMA4(A3, U, (W0).w); \
    FMA4(A4, U, (W1).x); FMA4(A5, U, (W1).y); FMA4(A6, U, (W1).z); FMA4(A7, U, (W1).w); \
    FMA4(B0, V, (W0).x); FMA4(B1, V, (W0).y); FMA4(B2, V, (W0).z); FMA4(B3, V, (W0).w); \
    FMA4(B4, V, (W1).x); FMA4(B5, V, (W1).y); FMA4(B6, V, (W1).z); FMA4(B7, V, (W1).w);

// K1: y[b,d,p] = sum_c x[b,c,p] * rwT[c][d] for one 32-d half.
// NO LDS. Weights come off the SCALAR path: wave-uniform pointer
// (readfirstlane'd wave id) -> s_load, constant-cache-hot, no LDS pipe,
// no barriers, no staging. Thread = 8px x 8d = 16 named float4 accs.
// Occupancy now VGPR-capped (~4 waves/SIMD), not LDS-capped (R6: 2).
// launch_bounds(256,1): R6/R8 evidence - any higher min forces spills.
__global__ __launch_bounds__(256, 1) void k_reduce(const float* __restrict__ x,
                                                   const float* __restrict__ rwT,
                                                   float* __restrict__ y,
                                                   float* __restrict__ pooledsum) {
    const int t = threadIdx.x;
    const int lane = t & 63;
    const int wv = __builtin_amdgcn_readfirstlane(t >> 6);   // wave-uniform 0..3
    const int half = blockIdx.z;                   // d base = half*32
    const int b = blockIdx.y;
    const int p0 = blockIdx.x * 512 + lane * 4;    // px group0; group1 = +256
    const int dbase = half * 32 + wv * 8;

    const float* __restrict__ wp = rwT + dbase;    // wave-uniform base
    const float* __restrict__ xb = x + (size_t)b * NC * NHW + p0;

    float4 A0{0,0,0,0}, A1{0,0,0,0}, A2{0,0,0,0}, A3{0,0,0,0};
    float4 A4{0,0,0,0}, A5{0,0,0,0}, A6{0,0,0,0}, A7{0,0,0,0};
    float4 B0{0,0,0,0}, B1{0,0,0,0}, B2{0,0,0,0}, B3{0,0,0,0};
    float4 B4{0,0,0,0}, B5{0,0,0,0}, B6{0,0,0,0}, B7{0,0,0,0};

    // depth-2 channel pipeline, named vars only
    float4 u0 = *reinterpret_cast<const float4*>(xb);
    float4 v0 = *reinterpret_cast<const float4*>(xb + 256);
    float4 u1 = *reinterpret_cast<const float4*>(xb + NHW);
    float4 v1 = *reinterpret_cast<const float4*>(xb + NHW + 256);

    for (int c = 0; c < NC - 2; c += 2) {
        const float4 un0 = *reinterpret_cast<const float4*>(xb + (size_t)(c + 2) * NHW);
        const float4 vn0 = *reinterpret_cast<const float4*>(xb + (size_t)(c + 2) * NHW + 256);
        const float4 un1 = *reinterpret_cast<const float4*>(xb + (size_t)(c + 3) * NHW);
        const float4 vn1 = *reinterpret_cast<const float4*>(xb + (size_t)(c + 3) * NHW + 256);
        // wave-uniform weight loads (scalar path): 8 floats per channel
        const float4 w00 = *reinterpret_cast<const float4*>(wp + (size_t)c * NCR);
        const float4 w01 = *reinterpret_cast<const float4*>(wp + (size_t)c * NCR + 4);
        const float4 w10 = *reinterpret_cast<const float4*>(wp + (size_t)(c + 1) * NCR);
        const float4 w11 = *reinterpret_cast<const float4*>(wp + (size_t)(c + 1) * NCR + 4);
        KBODY8(u0, v0, w00, w01);
        KBODY8(u1, v1, w10, w11);
        u0 = un0; v0 = vn0; u1 = un1; v1 = vn1;
    }
    {   // peeled last two channels (254, 255)
        const float4 w00 = *reinterpret_cast<const float4*>(wp + (size_t)(NC - 2) * NCR);
        const float4 w01 = *reinterpret_cast<const float4*>(wp + (size_t)(NC - 2) * NCR + 4);
        const float4 w10 = *reinterpret_cast<const float4*>(wp + (size_t)(NC - 1) * NCR);
        const float4 w11 = *reinterpret_cast<const float4*>(wp + (size_t)(NC - 1) * NCR + 4);
        KBODY8(u0, v0, w00, w01);
        KBODY8(u1, v1, w10, w11);
    }

    float* yb = y + ((size_t)b * NCR + dbase) * NHW + p0;
#define YST(K, A, B) \
    *reinterpret_cast<float4*>(yb + (size_t)(K) * NHW) = A; \
    *reinterpret_cast<float4*>(yb + (size_t)(K) * NHW + 256) = B;
    YST(0, A0, B0); YST(1, A1, B1); YST(2, A2, B2); YST(3, A3, B3);
    YST(4, A4, B4); YST(5, A5, B5); YST(6, A6, B6); YST(7, A7, B7);
#undef YST

    float* ps = pooledsum + b * NCR + dbase;
#define PRED(K, A, B) { \
    float s_ = A.x + A.y + A.z + A.w + B.x + B.y + B.z + B.w; \
    _Pragma("unroll") \
    for (int o_ = 32; o_ > 0; o_ >>= 1) s_ += __shfl_down(s_, o_, 64); \
    if (lane == 0) atomicAdd(&ps[K], s_); }
    PRED(0, A0, B0); PRED(1, A1, B1); PRED(2, A2, B2); PRED(3, A3, B3);
    PRED(4, A4, B4); PRED(5, A5, B5); PRED(6, A6, B6); PRED(7, A7, B7);
#undef PRED
}

// K2: gamma[b,d] = sigmoid(relu(mean@w1^T+b1)@w2^T+b2); pooledsum -> mean
__global__ __launch_bounds__(512) void k_gate(const float* __restrict__ pooledsum,
                                              const float* __restrict__ w1,
                                              const float* __restrict__ b1,
                                              const float* __restrict__ w2,
                                              const float* __restrict__ b2,
                                              float* __restrict__ gamma) {
    __shared__ float hsh[NB][16];
    const int t = threadIdx.x;
    constexpr float inv = 1.f / (float)NHW;
    if (t < NB * 16) {
        const int b = t / 16, j = t % 16;
        float s = b1[j];
        for (int d = 0; d < NCR; ++d)
            s = fmaf(pooledsum[b * NCR + d] * inv, w1[j * NCR + d], s);
        hsh[b][j] = fmaxf(s, 0.f);
    }
    __syncthreads();
    const int b = t / NCR, d = t % NCR;
    float s = b2[d];
#pragma unroll
    for (int j = 0; j < 16; ++j) s = fmaf(hsh[b][j], w2[d * 16 + j], s);
    gamma[t] = 1.f / (1.f + expf(-s));
}

// K3a: per (b, 32x8 tile): stencil on y -> kappa -> logits -> m = 1+sigmoid
__global__ __launch_bounds__(256) void k_logits(const float* __restrict__ y,
                                                const float* __restrict__ gamma,
                                                const float* __restrict__ fw,
                                                float* __restrict__ m) {
    __shared__ float tile[TH + 2][TW + 2];           // 10 x 34
    __shared__ float coef[NCR];

    const int b = blockIdx.z;
    const int w0 = blockIdx.x * TW, h0 = blockIdx.y * TH;
    const int t = threadIdx.x;
    const int tx = t % TW, ty = t / TW;

    if (t < NCR) coef[t] = fw[t] + gamma[b * NCR + t] * fw[NCR + t];
    __syncthreads();

    const float* yb = y + (size_t)b * NCR * NHW;
    float logit = 0.f;

    for (int c = 0; c < NCR; ++c) {
        const float* yc = yb + (size_t)c * NHW;
        for (int i = t; i < (TH + 2) * (TW + 2); i += 256) {
            const int iy = i / (TW + 2), ix = i % (TW + 2);
            const int gh = h0 + iy - 1, gw = w0 + ix - 1;
            float v = 0.f;
            if (gh >= 0 && gh < NH && gw >= 0 && gw < NW) v = yc[gh * NW + gw];
            tile[iy][ix] = v;
        }
        __syncthreads();

        const float a00 = tile[ty][tx],     a01 = tile[ty][tx + 1],     a02 = tile[ty][tx + 2];
        const float a10 = tile[ty + 1][tx], a11 = tile[ty + 1][tx + 1], a12 = tile[ty + 1][tx + 2];
        const float a20 = tile[ty + 2][tx], a21 = tile[ty + 2][tx + 1], a22 = tile[ty + 2][tx + 2];

        const float mu = (a00 + a01 + a02 + a10 + a11 + a12 + a20 + a21 + a22) * (1.f / 9.f);
        const float gx = (a00 - a02 + 2.f * (a10 - a12) + a20 - a22) * 0.125f;
        const float gy = (a00 + 2.f * a01 + a02 - a20 - 2.f * a21 - a22) * 0.125f;
        const float kappa = 1.f - fabsf(a11 - mu) / (fabsf(gx) + fabsf(gy) + KEPS);
        logit = fmaf(kappa, coef[c], logit);
        __syncthreads();
    }

    const float a = 1.f / (1.f + expf(-logit));
    m[(size_t)b * NHW + (h0 + ty) * NW + (w0 + tx)] = 1.f + a;
}

// K3b: pure stream out = x * m. Block: 256 thr over 1024 px; 4 channels each.
__global__ __launch_bounds__(256) void k_mul(const float* __restrict__ x,
                                             const float* __restrict__ m,
                                             float* __restrict__ out) {
    const int b = blockIdx.z;
    const int c0 = blockIdx.y * 4;
    const int p = blockIdx.x * 1024 + threadIdx.x * 4;

    const float4 mv = *reinterpret_cast<const float4*>(m + (size_t)b * NHW + p);
    const size_t base = (size_t)b * NC * NHW + (size_t)c0 * NHW + p;
    const float* xp = x + base;
    float* op = out + base;

#pragma unroll
    for (int cc = 0; cc < 4; ++cc) {
        const float4 v = *reinterpret_cast<const float4*>(xp + (size_t)cc * NHW);
        float4 r;
        r.x = v.x * mv.x; r.y = v.y * mv.y; r.z = v.z * mv.z; r.w = v.w * mv.w;
        *reinterpret_cast<float4*>(op + (size_t)cc * NHW) = r;
    }
}

extern "C" void kernel_launch(void* const* d_in, const int* in_sizes, int n_in,
                              void* d_out, int out_size, void* d_ws, size_t ws_size,
                              hipStream_t stream) {
    const float* x  = (const float*)d_in[0];
    const float* rw = (const float*)d_in[1];
    const float* w1 = (const float*)d_in[2];
    const float* b1 = (const float*)d_in[3];
    const float* w2 = (const float*)d_in[4];
    const float* b2 = (const float*)d_in[5];
    const float* fw = (const float*)d_in[6];
    float* out = (float*)d_out;

    float* y      = (float*)d_ws;                       // 13,107,200 floats
    float* pooled = y + (size_t)NB * NCR * NHW;         // 512 floats (sums)
    float* gamma  = pooled + NB * NCR;                  // 512 floats
    float* rwT    = gamma + NB * NCR;                   // 16384 floats
    float* m      = rwT + NC * NCR;                     // 204800 floats

    k_tr<<<dim3(64), 256, 0, stream>>>(rw, rwT, pooled);
    k_reduce<<<dim3(NHW / 512, NB, 2), 256, 0, stream>>>(x, rwT, y, pooled);
    k_gate<<<dim3(1), 512, 0, stream>>>(pooled, w1, b1, w2, b2, gamma);
    k_logits<<<dim3(NW / TW, NH / TH, NB), 256, 0, stream>>>(y, gamma, fw, m);
    k_mul<<<dim3(NHW / 1024, NC / 4, NB), 256, 0, stream>>>(x, m, out);
}